// Round 7
// baseline (1012.532 us; speedup 1.0000x reference)
//
#include <hip/hip_runtime.h>
#include <math.h>

#define B_ 16
#define N_ 4096
#define D_ 64
#define H_ 128
#define K_ 32
#define NS_ 1024
#define R2_ 0.04f
#define CAP_ 1024

typedef short short8 __attribute__((ext_vector_type(8)));
typedef float f32x4 __attribute__((ext_vector_type(4)));
typedef unsigned short ushort_t;

static __device__ __forceinline__ short f2bf(float f) {
    unsigned u = __float_as_uint(f);
    unsigned r = (u + 0x7FFFu + ((u >> 16) & 1u)) >> 16;   // round-to-nearest-even
    return (short)r;
}

template<int CTRL, int RM>
static __device__ __forceinline__ unsigned dppmov(unsigned v) {
    // old = v -> masked/invalid lanes keep v (identity for max/min)
    return (unsigned)__builtin_amdgcn_update_dpp((int)v, (int)v, CTRL, RM, 0xF, false);
}

#define DPP_FMAX_STEP(CTRL, RM)                                           \
    {                                                                     \
        float n = __uint_as_float(dppmov<CTRL, RM>(__float_as_uint(wm))); \
        wm = fmaxf(wm, n);                                                \
    }

#define DPP_UMIN_STEP(CTRL, RM)                                           \
    {                                                                     \
        unsigned n = dppmov<CTRL, RM>(cand);                              \
        cand = n < cand ? n : cand;                                       \
    }

#define DPP_UMIN_STEP_V(var, CTRL, RM)                                    \
    {                                                                     \
        unsigned n = dppmov<CTRL, RM>(var);                               \
        var = n < var ? n : var;                                          \
    }

// ---------------- x -> bf16 pre-convert (RNE, identical to f2bf) ----------
__global__ __launch_bounds__(256) void cvt_kernel(
    const float* __restrict__ x, ushort_t* __restrict__ xb)
{
    const size_t i = ((size_t)blockIdx.x * 256 + threadIdx.x) * 8;
    float4 a = *(const float4*)(x + i);
    float4 c = *(const float4*)(x + i + 4);
    short8 o;
    o[0] = f2bf(a.x); o[1] = f2bf(a.y); o[2] = f2bf(a.z); o[3] = f2bf(a.w);
    o[4] = f2bf(c.x); o[5] = f2bf(c.y); o[6] = f2bf(c.z); o[7] = f2bf(c.w);
    *(short8*)(xb + i) = o;
}

// ---------------- FPS v7: one block (512 thr) per cloud ----------------
// 2 waves/SIMD so one wave's serial tail (barrier -> ds_read skey ->
// tournament -> readlane -> ds_read lpos4) overlaps the other wave's issue.
// Lean per-wave reduction: fp32-max DPP + ballot idx fast-path.
__global__ __launch_bounds__(512, 1) void fps_kernel(
    const float* __restrict__ pos, int* __restrict__ idx_i,
    float* __restrict__ idx_f, float* __restrict__ pos_s)
{
    __shared__ float4 lpos4[N_];                         // 64 KB
    __shared__ float4 sres[NS_];                         // 16 KB
    __shared__ unsigned long long skey[2][8];
    const int b = blockIdx.x;
    const int t = threadIdx.x;
    const int wv = t >> 6;
    const int lane = t & 63;
    const float* posb = pos + (size_t)b * N_ * 3;
    for (int p = t; p < N_; p += 512)
        lpos4[p] = make_float4(posb[3 * p + 0], posb[3 * p + 1], posb[3 * p + 2], 0.f);
    __syncthreads();

    float px[8], py[8], pz[8], dist[8];
#pragma unroll
    for (int j = 0; j < 8; ++j) {
        float4 v = lpos4[t + 512 * j];
        px[j] = v.x; py[j] = v.y; pz[j] = v.z;
        dist[j] = 1e10f;
    }
    unsigned curidx = 0;
    float4 c0 = lpos4[0];
    float ccx = c0.x, ccy = c0.y, ccz = c0.z;

    for (int ns = 0; ns < NS_; ++ns) {
        if (t == 0)
            sres[ns] = make_float4(ccx, ccy, ccz, __uint_as_float(curidx));
        // ---- update dists + per-lane argmax (bit-exact d2 chain) ----
        float bv = -1.f; int bj = 0;
#pragma unroll
        for (int j = 0; j < 8; ++j) {
            float dx = __fsub_rn(px[j], ccx);
            float dy = __fsub_rn(py[j], ccy);
            float dz = __fsub_rn(pz[j], ccz);
            float d2 = __fadd_rn(__fadd_rn(__fmul_rn(dx, dx), __fmul_rn(dy, dy)), __fmul_rn(dz, dz));
            float dn = fminf(dist[j], d2);
            dist[j] = dn;
            bool g = dn > bv;                 // strict > + ascending j => lowest idx on tie
            bv = g ? dn : bv;
            bj = g ? j : bj;
        }
        // ---- wave fp32 max via DPP (result valid in lane 63) ----
        float wm = bv;
        DPP_FMAX_STEP(0x111, 0xF)   // row_shr:1
        DPP_FMAX_STEP(0x112, 0xF)   // row_shr:2
        DPP_FMAX_STEP(0x114, 0xF)   // row_shr:4
        DPP_FMAX_STEP(0x118, 0xF)   // row_shr:8
        DPP_FMAX_STEP(0x142, 0xA)   // row_bcast:15
        DPP_FMAX_STEP(0x143, 0xC)   // row_bcast:31
        const float wavemax = __uint_as_float(
            (unsigned)__builtin_amdgcn_readlane((int)__float_as_uint(wm), 63));
        // ---- min global idx among max-achieving lanes ----
        const unsigned pidx = (unsigned)t | ((unsigned)bj << 9);   // == global point idx
        const unsigned long long mask = __ballot(bv == wavemax);
        unsigned widx;
        if (__popcll(mask) == 1) {             // unique winner (common case)
            const int wl = __ffsll((long long)mask) - 1;
            widx = (unsigned)__builtin_amdgcn_readlane((int)pidx, wl);
        } else {                                // exact tie fallback
            unsigned cand = (bv == wavemax) ? pidx : 0xFFFFFFFFu;
            DPP_UMIN_STEP(0x111, 0xF)
            DPP_UMIN_STEP(0x112, 0xF)
            DPP_UMIN_STEP(0x114, 0xF)
            DPP_UMIN_STEP(0x118, 0xF)
            DPP_UMIN_STEP(0x142, 0xA)
            DPP_UMIN_STEP(0x143, 0xC)
            widx = (unsigned)__builtin_amdgcn_readlane((int)cand, 63);
        }
        if (lane == 0)
            skey[ns & 1][wv] = (((unsigned long long)__float_as_uint(wavemax)) << 32)
                             | (unsigned long long)(0xFFFFFFFFu - widx);
        __syncthreads();
        // ---- 8-slot u64-max tournament via DPP row_shl (lane 0 holds winner) ----
        {
            unsigned long long skv = skey[ns & 1][lane & 7];
            unsigned kh2 = (unsigned)(skv >> 32), kl2 = (unsigned)skv;
#define SLOT_STEP(CTRL)                                                        \
            {                                                                  \
                unsigned nh = dppmov<CTRL, 0xF>(kh2);                          \
                unsigned nl = dppmov<CTRL, 0xF>(kl2);                          \
                unsigned long long nk = (((unsigned long long)nh) << 32) | nl; \
                unsigned long long ok = (((unsigned long long)kh2) << 32) | kl2;\
                if (nk > ok) { kh2 = nh; kl2 = nl; }                           \
            }
            SLOT_STEP(0x101)   // row_shl:1
            SLOT_STEP(0x102)   // row_shl:2
            SLOT_STEP(0x104)   // row_shl:4
#undef SLOT_STEP
            curidx = 0xFFFFFFFFu - (unsigned)__builtin_amdgcn_readlane((int)kl2, 0);
        }
        // winner coords: one broadcast LDS read (same address, all lanes)
        {
            float4 cc = lpos4[curidx];
            ccx = cc.x; ccy = cc.y; ccz = cc.z;
        }
    }
    __syncthreads();
    for (int i = t; i < NS_; i += 512) {
        float4 r = sres[i];
        unsigned id = __float_as_uint(r.w);
        idx_i[b * NS_ + i] = (int)id;
        idx_f[b * NS_ + i] = (float)id;
        pos_s[(b * NS_ + i) * 3 + 0] = r.x;
        pos_s[(b * NS_ + i) * 3 + 1] = r.y;
        pos_s[(b * NS_ + i) * 3 + 2] = r.z;
    }
}

// ---------------- radius-KNN v5: split-phase (d2-min DPP + ballot) --------
__global__ __launch_bounds__(256) void nbr_kernel(
    const float* __restrict__ pos, const float* __restrict__ pos_s,
    int* __restrict__ nbr, float* __restrict__ cntv)
{
    __shared__ unsigned long long ck[4][CAP_];
    const int w = threadIdx.x >> 6;
    const int lane = threadIdx.x & 63;
    const int s = blockIdx.x * 4 + w;
    const int b = s >> 10;
    const float cx = pos_s[s * 3 + 0], cy = pos_s[s * 3 + 1], cz = pos_s[s * 3 + 2];
    const float* posb = pos + (size_t)b * N_ * 3;
    int m = 0;
    for (int base = 0; base < N_; base += 64) {
        int p = base + lane;
        float dx = __fsub_rn(posb[3 * p + 0], cx);
        float dy = __fsub_rn(posb[3 * p + 1], cy);
        float dz = __fsub_rn(posb[3 * p + 2], cz);
        float d2 = __fadd_rn(__fadd_rn(__fmul_rn(dx, dx), __fmul_rn(dy, dy)), __fmul_rn(dz, dz));
        bool in = (d2 <= R2_);
        unsigned long long msk = __ballot(in);
        int before = __popcll(msk & ((1ull << lane) - 1ull));
        int slot = m + before;
        if (in && slot < CAP_)
            ck[w][slot] = ((unsigned long long)__float_as_uint(d2) << 32) | (unsigned)p;
        m += __popcll(msk);
    }
    if (m > CAP_) m = CAP_;
    __asm__ volatile("s_waitcnt lgkmcnt(0)" ::: "memory");
    int kcnt = m < K_ ? m : K_;
    if (m <= 256) {
        // register-resident candidates; selection = u64 local scan +
        // u32 d2-min DPP + ballot winner (exact idx-umin fallback on ties)
        unsigned long long kr[4];
#pragma unroll
        for (int r = 0; r < 4; ++r) {
            int q = r * 64 + lane;
            unsigned long long v = ck[w][q & (CAP_ - 1)];
            kr[r] = (q < m) ? v : ~0ull;
        }
        unsigned chosen = 0;
        for (int k = 0; k < kcnt; ++k) {
            unsigned long long localk = ~0ull; int br = -1;
#pragma unroll
            for (int r = 0; r < 4; ++r) {
                bool ok = (!((chosen >> r) & 1u)) && (kr[r] < localk);
                localk = ok ? kr[r] : localk;
                br = ok ? r : br;
            }
            const unsigned mybits = (unsigned)(localk >> 32);
            const unsigned myidx = (unsigned)localk;
            unsigned wb = mybits;
            DPP_UMIN_STEP_V(wb, 0x111, 0xF)
            DPP_UMIN_STEP_V(wb, 0x112, 0xF)
            DPP_UMIN_STEP_V(wb, 0x114, 0xF)
            DPP_UMIN_STEP_V(wb, 0x118, 0xF)
            DPP_UMIN_STEP_V(wb, 0x142, 0xA)
            DPP_UMIN_STEP_V(wb, 0x143, 0xC)
            const unsigned minbits = (unsigned)__builtin_amdgcn_readlane((int)wb, 63);
            const unsigned long long wmask = __ballot(mybits == minbits);
            unsigned widx;
            if (__popcll(wmask) == 1) {
                const int wl = __ffsll((long long)wmask) - 1;
                widx = (unsigned)__builtin_amdgcn_readlane((int)myidx, wl);
            } else {
                unsigned cand = (mybits == minbits) ? myidx : 0xFFFFFFFFu;
                DPP_UMIN_STEP(0x111, 0xF)
                DPP_UMIN_STEP(0x112, 0xF)
                DPP_UMIN_STEP(0x114, 0xF)
                DPP_UMIN_STEP(0x118, 0xF)
                DPP_UMIN_STEP(0x142, 0xA)
                DPP_UMIN_STEP(0x143, 0xC)
                widx = (unsigned)__builtin_amdgcn_readlane((int)cand, 63);
            }
            if (mybits == minbits && myidx == widx) chosen |= 1u << br;
            if (lane == 0) nbr[s * K_ + k] = (int)widx;
        }
    } else {
        // exact fallback (rare): LDS-scan selection with u64 DPP min
        unsigned chosen = 0;
        for (int k = 0; k < kcnt; ++k) {
            unsigned long long localk = ~0ull; int bslot = -1;
            for (int r = 0; r * 64 + lane < m; ++r) {
                if (chosen & (1u << r)) continue;
                int q = r * 64 + lane;
                unsigned long long key = ck[w][q];
                if (key < localk) { localk = key; bslot = q; }
            }
            unsigned kh = (unsigned)(localk >> 32), kl = (unsigned)localk;
#define DPP_MIN_STEP2(CTRL, RM)                                           \
            {                                                             \
                unsigned nh = dppmov<CTRL, RM>(kh);                       \
                unsigned nl = dppmov<CTRL, RM>(kl);                       \
                unsigned long long nk = (((unsigned long long)nh) << 32) | nl; \
                unsigned long long ok = (((unsigned long long)kh) << 32) | kl; \
                if (nk < ok) { kh = nh; kl = nl; }                        \
            }
            DPP_MIN_STEP2(0x111, 0xF)
            DPP_MIN_STEP2(0x112, 0xF)
            DPP_MIN_STEP2(0x114, 0xF)
            DPP_MIN_STEP2(0x118, 0xF)
            DPP_MIN_STEP2(0x142, 0xA)
            DPP_MIN_STEP2(0x143, 0xC)
#undef DPP_MIN_STEP2
            unsigned mh = (unsigned)__builtin_amdgcn_readlane((int)kh, 63);
            unsigned ml = (unsigned)__builtin_amdgcn_readlane((int)kl, 63);
            unsigned long long bk = (((unsigned long long)mh) << 32) | ml;
            if (localk == bk && bslot >= 0) chosen |= 1u << (bslot >> 6);
            if (lane == 0) nbr[s * K_ + k] = (int)(bk & 0xFFFFFFFFull);
        }
    }
    if (lane == 0) {
        for (int k = kcnt; k < K_; ++k) nbr[s * K_ + k] = -1;
        cntv[s] = (float)kcnt;
    }
}

// ---------------- message MLP v5: bf16 MFMA, pre-converted x ----------------
__global__ __launch_bounds__(256) void msg_kernel(
    const ushort_t* __restrict__ xb, const float* __restrict__ pos,
    const float* __restrict__ W1, const float* __restrict__ b1,
    const float* __restrict__ W2, const float* __restrict__ b2,
    const float* __restrict__ pos_s, const int* __restrict__ nbr,
    const float* __restrict__ cntv, float* __restrict__ aggr_x,
    float* __restrict__ out_pos)
{
    __shared__ __align__(16) char smem[4 * 5120];
    const int t = threadIdx.x;
    const int wv = t >> 6, lane = t & 63;
    const int quad = lane >> 4, cl = lane & 15;
    char* wb = smem + wv * 5120;

    short8 bfrag[8][2];
    float b1v[8], w1dv[8], w2v0[8], w2v1[8], w2v2[8];
#pragma unroll
    for (int Nt = 0; Nt < 8; ++Nt) {
        const int h = Nt * 16 + cl;
#pragma unroll
        for (int ks = 0; ks < 2; ++ks) {
            short8 f;
#pragma unroll
            for (int jj = 0; jj < 8; ++jj)
                f[jj] = f2bf(W1[(ks * 32 + quad * 8 + jj) * H_ + h]);
            bfrag[Nt][ks] = f;
        }
        b1v[Nt] = b1[h];
        w1dv[Nt] = W1[64 * H_ + h];
        w2v0[Nt] = W2[h * 3 + 0];
        w2v1[Nt] = W2[h * 3 + 1];
        w2v2[Nt] = W2[h * 3 + 2];
    }
    const float b20 = b2[0], b21 = b2[1], b22 = b2[2];

    const int kkg = lane >> 1, half = lane & 1;
    for (int i = 0; i < 4; ++i) {
        const int s = blockIdx.x * 16 + wv * 4 + i;
        const int b = s >> 10;
        const int n = nbr[s * K_ + kkg];
        {
            char* frow = wb + kkg * 144 + half * 64;
            if (n >= 0) {
                const short8* xr = (const short8*)(xb + ((size_t)b * N_ + n) * D_) + half * 4;
#pragma unroll
                for (int q = 0; q < 4; ++q) *(short8*)(frow + q * 16) = xr[q];
            } else {
                short8 z = {0, 0, 0, 0, 0, 0, 0, 0};
#pragma unroll
                for (int q = 0; q < 4; ++q) *(short8*)(frow + q * 16) = z;
            }
            if (half == 0) {
                float dxm = 0.f, dym = 0.f, dzm = 0.f, de = -1.f;
                if (n >= 0) {
                    const float* pj = pos + ((size_t)b * N_ + n) * 3;
                    float dx = pj[0] - pos_s[s * 3 + 0];
                    float dy = pj[1] - pos_s[s * 3 + 1];
                    float dz = pj[2] - pos_s[s * 3 + 2];
                    float d2 = dx * dx + dy * dy + dz * dz;
                    de = d2 > 0.f ? sqrtf(d2) : 0.f;
                    dxm = dx; dym = dy; dzm = dz;
                }
                f32x4 sv = {dxm, dym, dzm, de};
                *(f32x4*)(wb + 4608 + kkg * 16) = sv;
            }
        }
        float agp[8] = {0, 0, 0, 0, 0, 0, 0, 0};
        float gp0[8] = {0, 0, 0, 0, 0, 0, 0, 0};
        float gp1[8] = {0, 0, 0, 0, 0, 0, 0, 0};
        float gp2[8] = {0, 0, 0, 0, 0, 0, 0, 0};
#pragma unroll
        for (int Mt = 0; Mt < 2; ++Mt) {
            short8 a0 = *(short8*)(wb + (Mt * 16 + cl) * 144 + quad * 16);
            short8 a1 = *(short8*)(wb + (Mt * 16 + cl) * 144 + 64 + quad * 16);
            f32x4 acc[8];
#pragma unroll
            for (int Nt = 0; Nt < 8; ++Nt) {
                f32x4 z = {0.f, 0.f, 0.f, 0.f};
                z = __builtin_amdgcn_mfma_f32_16x16x32_bf16(a0, bfrag[Nt][0], z, 0, 0, 0);
                z = __builtin_amdgcn_mfma_f32_16x16x32_bf16(a1, bfrag[Nt][1], z, 0, 0, 0);
                acc[Nt] = z;
            }
            f32x4 sd[4];
#pragma unroll
            for (int r = 0; r < 4; ++r)
                sd[r] = *(f32x4*)(wb + 4608 + (Mt * 16 + quad * 4 + r) * 16);
#pragma unroll
            for (int Nt = 0; Nt < 8; ++Nt) {
#pragma unroll
                for (int r = 0; r < 4; ++r) {
                    float dr = sd[r][3];
                    float wgt = dr >= 0.f ? 1.f : 0.f;
                    float dd = dr >= 0.f ? dr : 0.f;
                    float e = fmaf(dd, w1dv[Nt], acc[Nt][r]) + b1v[Nt];
                    e = e > 0.f ? e : 0.f;
                    agp[Nt] = fmaf(wgt, e, agp[Nt]);
                    gp0[Nt] = fmaf(sd[r][0], e, gp0[Nt]);
                    gp1[Nt] = fmaf(sd[r][1], e, gp1[Nt]);
                    gp2[Nt] = fmaf(sd[r][2], e, gp2[Nt]);
                }
            }
        }
#pragma unroll
        for (int Nt = 0; Nt < 8; ++Nt) {
            float v = agp[Nt]; v += __shfl_xor(v, 16); v += __shfl_xor(v, 32);
            aggr_x[(size_t)s * H_ + Nt * 16 + cl] = v;
            float g0 = gp0[Nt]; g0 += __shfl_xor(g0, 16); g0 += __shfl_xor(g0, 32); gp0[Nt] = g0;
            float g1 = gp1[Nt]; g1 += __shfl_xor(g1, 16); g1 += __shfl_xor(g1, 32); gp1[Nt] = g1;
            float g2 = gp2[Nt]; g2 += __shfl_xor(g2, 16); g2 += __shfl_xor(g2, 32); gp2[Nt] = g2;
        }
        float pr0 = 0.f, pr1 = 0.f, pr2 = 0.f;
#pragma unroll
        for (int Nt = 0; Nt < 8; ++Nt) {
            pr0 = fmaf(w2v0[Nt], gp0[Nt], pr0);
            pr1 = fmaf(w2v1[Nt], gp1[Nt], pr1);
            pr2 = fmaf(w2v2[Nt], gp2[Nt], pr2);
        }
#pragma unroll
        for (int off = 1; off < 16; off <<= 1) {
            pr0 += __shfl_xor(pr0, off);
            pr1 += __shfl_xor(pr1, off);
            pr2 += __shfl_xor(pr2, off);
        }
        f32x4 dsv = *(f32x4*)(wb + 4608 + (lane & 31) * 16);
        float q0 = dsv[0], q1 = dsv[1], q2 = dsv[2];
#pragma unroll
        for (int off = 1; off < 32; off <<= 1) {
            q0 += __shfl_xor(q0, off);
            q1 += __shfl_xor(q1, off);
            q2 += __shfl_xor(q2, off);
        }
        float cnt = cntv[s]; if (cnt < 1.f) cnt = 1.f;
        if (lane < 3) {
            float pr = lane == 0 ? pr0 : (lane == 1 ? pr1 : pr2);
            float qq = lane == 0 ? q0 : (lane == 1 ? q1 : q2);
            float bb = lane == 0 ? b20 : (lane == 1 ? b21 : b22);
            out_pos[s * 3 + lane] = pos_s[s * 3 + lane] + (pr + bb * qq) / cnt;
        }
    }
}

// ---------------- update GEMM: relu([x_d, aggr_x] @ W3 + b3) ----------------
__global__ __launch_bounds__(128) void out_kernel(
    const float* __restrict__ x, const float* __restrict__ W3,
    const float* __restrict__ b3, const int* __restrict__ idx_i,
    const float* __restrict__ aggr_x, float* __restrict__ out_x)
{
    __shared__ float rows[32][208];
    const int t = threadIdx.x;
    const int s0 = blockIdx.x * 32;
    const int sl = t >> 2, part = t & 3;
    const int s = s0 + sl;
    const int b = s >> 10;
    const int id = idx_i[s];
    {
        const float4* xr = (const float4*)(x + ((size_t)b * N_ + id) * D_);
        float4* rr = (float4*)&rows[sl][0];
#pragma unroll
        for (int q = 0; q < 4; ++q) rr[part * 4 + q] = xr[part * 4 + q];
        const float4* ar = (const float4*)(aggr_x + (size_t)s * H_);
        float4* rr2 = (float4*)&rows[sl][64];
#pragma unroll
        for (int q = 0; q < 8; ++q) rr2[part * 8 + q] = ar[part * 8 + q];
    }
    __syncthreads();
    float acc[32];
#pragma unroll
    for (int i = 0; i < 32; ++i) acc[i] = 0.f;
    for (int j4 = 0; j4 < 48; ++j4) {
        float w0 = W3[(j4 * 4 + 0) * H_ + t];
        float w1 = W3[(j4 * 4 + 1) * H_ + t];
        float w2 = W3[(j4 * 4 + 2) * H_ + t];
        float w3 = W3[(j4 * 4 + 3) * H_ + t];
#pragma unroll
        for (int i = 0; i < 32; ++i) {
            const float4 f = *(const float4*)&rows[i][j4 * 4];
            float a = acc[i];
            a = fmaf(f.x, w0, a); a = fmaf(f.y, w1, a);
            a = fmaf(f.z, w2, a); a = fmaf(f.w, w3, a);
            acc[i] = a;
        }
    }
    const float bb = b3[t];
#pragma unroll
    for (int i = 0; i < 32; ++i) {
        float v = acc[i] + bb;
        v = v > 0.f ? v : 0.f;
        out_x[(size_t)(s0 + i) * H_ + t] = v;
    }
}

extern "C" void kernel_launch(void* const* d_in, const int* in_sizes, int n_in,
                              void* d_out, int out_size, void* d_ws, size_t ws_size,
                              hipStream_t stream) {
    const float* x   = (const float*)d_in[0];
    const float* pos = (const float*)d_in[1];
    const float* W1  = (const float*)d_in[2];
    const float* b1  = (const float*)d_in[3];
    const float* W2  = (const float*)d_in[4];
    const float* b2  = (const float*)d_in[5];
    const float* W3  = (const float*)d_in[6];
    const float* b3  = (const float*)d_in[7];

    float* out_x   = (float*)d_out;                       // [16,1024,128]
    float* out_pos = (float*)d_out + 2097152;             // [16,1024,3]
    float* idx_f   = (float*)d_out + 2146304;             // [16,1024] as float

    char* ws = (char*)d_ws;
    int*      idx_i  = (int*)ws;                   // 16384 ints
    float*    pos_s  = (float*)(ws + 65536);       // 49152 floats
    int*      nbr    = (int*)(ws + 262144);        // 524288 ints
    float*    cntv   = (float*)(ws + 2359296);     // 16384 floats
    float*    aggr_x = (float*)(ws + 2424832);     // 2097152 floats
    ushort_t* x_bf16 = (ushort_t*)(ws + 10813440); // 16777216 ushorts (ends ~19.2MB)

    cvt_kernel<<<(B_ * N_ * D_) / (256 * 8), 256, 0, stream>>>(x, x_bf16);
    fps_kernel<<<B_, 512, 0, stream>>>(pos, idx_i, idx_f, pos_s);
    nbr_kernel<<<(B_ * NS_) / 4, 256, 0, stream>>>(pos, pos_s, nbr, cntv);
    msg_kernel<<<(B_ * NS_) / 16, 256, 0, stream>>>(x_bf16, pos, W1, b1, W2, b2,
                                                    pos_s, nbr, cntv, aggr_x, out_pos);
    out_kernel<<<(B_ * NS_) / 32, 128, 0, stream>>>(x, W3, b3, idx_i, aggr_x, out_x);
}

// Round 8
// 967.062 us; speedup vs baseline: 1.0470x; 1.0470x over previous
//
#include <hip/hip_runtime.h>
#include <math.h>

#define B_ 16
#define N_ 4096
#define D_ 64
#define H_ 128
#define K_ 32
#define NS_ 1024
#define R2_ 0.04f
#define CAP_ 1024

typedef short short8 __attribute__((ext_vector_type(8)));
typedef float f32x4 __attribute__((ext_vector_type(4)));
typedef unsigned short ushort_t;

static __device__ __forceinline__ short f2bf(float f) {
    unsigned u = __float_as_uint(f);
    unsigned r = (u + 0x7FFFu + ((u >> 16) & 1u)) >> 16;   // round-to-nearest-even
    return (short)r;
}

template<int CTRL, int RM>
static __device__ __forceinline__ unsigned dppmov(unsigned v) {
    // old = v -> masked/invalid lanes keep v (identity for max/min)
    return (unsigned)__builtin_amdgcn_update_dpp((int)v, (int)v, CTRL, RM, 0xF, false);
}

#define DPP_FMAX_STEP(CTRL, RM)                                           \
    {                                                                     \
        float n = __uint_as_float(dppmov<CTRL, RM>(__float_as_uint(wm))); \
        wm = fmaxf(wm, n);                                                \
    }

#define DPP_UMIN_STEP(CTRL, RM)                                           \
    {                                                                     \
        unsigned n = dppmov<CTRL, RM>(cand);                              \
        cand = n < cand ? n : cand;                                       \
    }

#define DPP_UMIN_STEP_V(var, CTRL, RM)                                    \
    {                                                                     \
        unsigned n = dppmov<CTRL, RM>(var);                               \
        var = n < var ? n : var;                                          \
    }

// ---------------- x -> bf16 pre-convert (RNE, identical to f2bf) ----------
__global__ __launch_bounds__(256) void cvt_kernel(
    const float* __restrict__ x, ushort_t* __restrict__ xb)
{
    const size_t i = ((size_t)blockIdx.x * 256 + threadIdx.x) * 8;
    float4 a = *(const float4*)(x + i);
    float4 c = *(const float4*)(x + i + 4);
    short8 o;
    o[0] = f2bf(a.x); o[1] = f2bf(a.y); o[2] = f2bf(a.z); o[3] = f2bf(a.w);
    o[4] = f2bf(c.x); o[5] = f2bf(c.y); o[6] = f2bf(c.z); o[7] = f2bf(c.w);
    *(short8*)(xb + i) = o;
}

// ---------------- FPS v8: one block (256 thr) per cloud ----------------
// v6 reduction (fp32-max DPP + ballot idx fast-path) + restructured tail:
// winner coords prefetched from lpos4 BEFORE the barrier and carried through
// the slot tournament via a slot-id + v_readlane (SGPR index) — removes the
// second dependent ~120-cyc LDS read from the per-iteration critical path.
__global__ __launch_bounds__(256, 1) void fps_kernel(
    const float* __restrict__ pos, int* __restrict__ idx_i,
    float* __restrict__ idx_f, float* __restrict__ pos_s)
{
    __shared__ float4 lpos4[N_];                         // 64 KB
    __shared__ float4 sres[NS_];                         // 16 KB
    __shared__ unsigned long long skey[2][4];
    __shared__ float4 scoord[2][4];
    const int b = blockIdx.x;
    const int t = threadIdx.x;
    const int wv = t >> 6;
    const int lane = t & 63;
    const float* posb = pos + (size_t)b * N_ * 3;
    for (int p = t; p < N_; p += 256)
        lpos4[p] = make_float4(posb[3 * p + 0], posb[3 * p + 1], posb[3 * p + 2], 0.f);
    __syncthreads();

    float px[16], py[16], pz[16], dist[16];
#pragma unroll
    for (int j = 0; j < 16; ++j) {
        float4 v = lpos4[t + 256 * j];
        px[j] = v.x; py[j] = v.y; pz[j] = v.z;
        dist[j] = 1e10f;
    }
    unsigned curidx = 0;
    float4 c0 = lpos4[0];
    float ccx = c0.x, ccy = c0.y, ccz = c0.z;

    for (int ns = 0; ns < NS_; ++ns) {
        if (t == 0)
            sres[ns] = make_float4(ccx, ccy, ccz, __uint_as_float(curidx));
        // ---- update dists + per-lane argmax (bit-exact d2 chain) ----
        float bv = -1.f; int bj = 0;
#pragma unroll
        for (int j = 0; j < 16; ++j) {
            float dx = __fsub_rn(px[j], ccx);
            float dy = __fsub_rn(py[j], ccy);
            float dz = __fsub_rn(pz[j], ccz);
            float d2 = __fadd_rn(__fadd_rn(__fmul_rn(dx, dx), __fmul_rn(dy, dy)), __fmul_rn(dz, dz));
            float dn = fminf(dist[j], d2);
            dist[j] = dn;
            bool g = dn > bv;                 // strict > + ascending j => lowest idx on tie
            bv = g ? dn : bv;
            bj = g ? j : bj;
        }
        // ---- wave fp32 max via DPP (result valid in lane 63) ----
        float wm = bv;
        DPP_FMAX_STEP(0x111, 0xF)   // row_shr:1
        DPP_FMAX_STEP(0x112, 0xF)   // row_shr:2
        DPP_FMAX_STEP(0x114, 0xF)   // row_shr:4
        DPP_FMAX_STEP(0x118, 0xF)   // row_shr:8
        DPP_FMAX_STEP(0x142, 0xA)   // row_bcast:15
        DPP_FMAX_STEP(0x143, 0xC)   // row_bcast:31
        const float wavemax = __uint_as_float(
            (unsigned)__builtin_amdgcn_readlane((int)__float_as_uint(wm), 63));
        // ---- min global idx among max-achieving lanes ----
        const unsigned pidx = (unsigned)t + ((unsigned)bj << 8);   // == global point idx
        const unsigned long long mask = __ballot(bv == wavemax);
        unsigned widx;
        if (__popcll(mask) == 1) {             // unique winner (common case)
            const int wl = __ffsll((long long)mask) - 1;
            widx = (unsigned)__builtin_amdgcn_readlane((int)pidx, wl);
        } else {                                // exact tie fallback
            unsigned cand = (bv == wavemax) ? pidx : 0xFFFFFFFFu;
            DPP_UMIN_STEP(0x111, 0xF)
            DPP_UMIN_STEP(0x112, 0xF)
            DPP_UMIN_STEP(0x114, 0xF)
            DPP_UMIN_STEP(0x118, 0xF)
            DPP_UMIN_STEP(0x142, 0xA)
            DPP_UMIN_STEP(0x143, 0xC)
            widx = (unsigned)__builtin_amdgcn_readlane((int)cand, 63);
        }
        // prefetch this wave's winner coords (broadcast, uniform addr) so the
        // coord fetch latency hides under the key store + barrier wait
        float4 wc = lpos4[widx];
        if (lane == 0) {
            skey[ns & 1][wv] = (((unsigned long long)__float_as_uint(wavemax)) << 32)
                             | (unsigned long long)(0xFFFFFFFFu - widx);
            scoord[ns & 1][wv] = wc;
        }
        __syncthreads();
        // ---- 4-slot u64-max tournament (carrying slot id); coords via
        //      v_readlane from the slot-holder lane (no second LDS read) ----
        {
            unsigned sid = (unsigned)(lane & 3);
            unsigned long long skv = skey[ns & 1][sid];
            float4 scv = scoord[ns & 1][sid];
            unsigned kh2 = (unsigned)(skv >> 32), kl2 = (unsigned)skv;
#define SLOT_STEP(CTRL)                                                        \
            {                                                                  \
                unsigned nh = dppmov<CTRL, 0xF>(kh2);                          \
                unsigned nl = dppmov<CTRL, 0xF>(kl2);                          \
                unsigned nsid = dppmov<CTRL, 0xF>(sid);                        \
                unsigned long long nk = (((unsigned long long)nh) << 32) | nl; \
                unsigned long long ok = (((unsigned long long)kh2) << 32) | kl2;\
                if (nk > ok) { kh2 = nh; kl2 = nl; sid = nsid; }               \
            }
            SLOT_STEP(0x101)   // row_shl:1
            SLOT_STEP(0x102)   // row_shl:2
#undef SLOT_STEP
            const int slotwin = __builtin_amdgcn_readfirstlane((int)sid);
            curidx = 0xFFFFFFFFu - (unsigned)__builtin_amdgcn_readfirstlane((int)kl2);
            ccx = __uint_as_float((unsigned)__builtin_amdgcn_readlane(
                      (int)__float_as_uint(scv.x), slotwin));
            ccy = __uint_as_float((unsigned)__builtin_amdgcn_readlane(
                      (int)__float_as_uint(scv.y), slotwin));
            ccz = __uint_as_float((unsigned)__builtin_amdgcn_readlane(
                      (int)__float_as_uint(scv.z), slotwin));
        }
    }
    __syncthreads();
    for (int i = t; i < NS_; i += 256) {
        float4 r = sres[i];
        unsigned id = __float_as_uint(r.w);
        idx_i[b * NS_ + i] = (int)id;
        idx_f[b * NS_ + i] = (float)id;
        pos_s[(b * NS_ + i) * 3 + 0] = r.x;
        pos_s[(b * NS_ + i) * 3 + 1] = r.y;
        pos_s[(b * NS_ + i) * 3 + 2] = r.z;
    }
}

// ---------------- radius-KNN v5: split-phase (d2-min DPP + ballot) --------
__global__ __launch_bounds__(256) void nbr_kernel(
    const float* __restrict__ pos, const float* __restrict__ pos_s,
    int* __restrict__ nbr, float* __restrict__ cntv)
{
    __shared__ unsigned long long ck[4][CAP_];
    const int w = threadIdx.x >> 6;
    const int lane = threadIdx.x & 63;
    const int s = blockIdx.x * 4 + w;
    const int b = s >> 10;
    const float cx = pos_s[s * 3 + 0], cy = pos_s[s * 3 + 1], cz = pos_s[s * 3 + 2];
    const float* posb = pos + (size_t)b * N_ * 3;
    int m = 0;
    for (int base = 0; base < N_; base += 64) {
        int p = base + lane;
        float dx = __fsub_rn(posb[3 * p + 0], cx);
        float dy = __fsub_rn(posb[3 * p + 1], cy);
        float dz = __fsub_rn(posb[3 * p + 2], cz);
        float d2 = __fadd_rn(__fadd_rn(__fmul_rn(dx, dx), __fmul_rn(dy, dy)), __fmul_rn(dz, dz));
        bool in = (d2 <= R2_);
        unsigned long long msk = __ballot(in);
        int before = __popcll(msk & ((1ull << lane) - 1ull));
        int slot = m + before;
        if (in && slot < CAP_)
            ck[w][slot] = ((unsigned long long)__float_as_uint(d2) << 32) | (unsigned)p;
        m += __popcll(msk);
    }
    if (m > CAP_) m = CAP_;
    __asm__ volatile("s_waitcnt lgkmcnt(0)" ::: "memory");
    int kcnt = m < K_ ? m : K_;
    if (m <= 256) {
        // register-resident candidates; selection = u64 local scan +
        // u32 d2-min DPP + ballot winner (exact idx-umin fallback on ties)
        unsigned long long kr[4];
#pragma unroll
        for (int r = 0; r < 4; ++r) {
            int q = r * 64 + lane;
            unsigned long long v = ck[w][q & (CAP_ - 1)];
            kr[r] = (q < m) ? v : ~0ull;
        }
        unsigned chosen = 0;
        for (int k = 0; k < kcnt; ++k) {
            unsigned long long localk = ~0ull; int br = -1;
#pragma unroll
            for (int r = 0; r < 4; ++r) {
                bool ok = (!((chosen >> r) & 1u)) && (kr[r] < localk);
                localk = ok ? kr[r] : localk;
                br = ok ? r : br;
            }
            const unsigned mybits = (unsigned)(localk >> 32);
            const unsigned myidx = (unsigned)localk;
            unsigned wb = mybits;
            DPP_UMIN_STEP_V(wb, 0x111, 0xF)
            DPP_UMIN_STEP_V(wb, 0x112, 0xF)
            DPP_UMIN_STEP_V(wb, 0x114, 0xF)
            DPP_UMIN_STEP_V(wb, 0x118, 0xF)
            DPP_UMIN_STEP_V(wb, 0x142, 0xA)
            DPP_UMIN_STEP_V(wb, 0x143, 0xC)
            const unsigned minbits = (unsigned)__builtin_amdgcn_readlane((int)wb, 63);
            const unsigned long long wmask = __ballot(mybits == minbits);
            unsigned widx;
            if (__popcll(wmask) == 1) {
                const int wl = __ffsll((long long)wmask) - 1;
                widx = (unsigned)__builtin_amdgcn_readlane((int)myidx, wl);
            } else {
                unsigned cand = (mybits == minbits) ? myidx : 0xFFFFFFFFu;
                DPP_UMIN_STEP(0x111, 0xF)
                DPP_UMIN_STEP(0x112, 0xF)
                DPP_UMIN_STEP(0x114, 0xF)
                DPP_UMIN_STEP(0x118, 0xF)
                DPP_UMIN_STEP(0x142, 0xA)
                DPP_UMIN_STEP(0x143, 0xC)
                widx = (unsigned)__builtin_amdgcn_readlane((int)cand, 63);
            }
            if (mybits == minbits && myidx == widx) chosen |= 1u << br;
            if (lane == 0) nbr[s * K_ + k] = (int)widx;
        }
    } else {
        // exact fallback (rare): LDS-scan selection with u64 DPP min
        unsigned chosen = 0;
        for (int k = 0; k < kcnt; ++k) {
            unsigned long long localk = ~0ull; int bslot = -1;
            for (int r = 0; r * 64 + lane < m; ++r) {
                if (chosen & (1u << r)) continue;
                int q = r * 64 + lane;
                unsigned long long key = ck[w][q];
                if (key < localk) { localk = key; bslot = q; }
            }
            unsigned kh = (unsigned)(localk >> 32), kl = (unsigned)localk;
#define DPP_MIN_STEP2(CTRL, RM)                                           \
            {                                                             \
                unsigned nh = dppmov<CTRL, RM>(kh);                       \
                unsigned nl = dppmov<CTRL, RM>(kl);                       \
                unsigned long long nk = (((unsigned long long)nh) << 32) | nl; \
                unsigned long long ok = (((unsigned long long)kh) << 32) | kl; \
                if (nk < ok) { kh = nh; kl = nl; }                        \
            }
            DPP_MIN_STEP2(0x111, 0xF)
            DPP_MIN_STEP2(0x112, 0xF)
            DPP_MIN_STEP2(0x114, 0xF)
            DPP_MIN_STEP2(0x118, 0xF)
            DPP_MIN_STEP2(0x142, 0xA)
            DPP_MIN_STEP2(0x143, 0xC)
#undef DPP_MIN_STEP2
            unsigned mh = (unsigned)__builtin_amdgcn_readlane((int)kh, 63);
            unsigned ml = (unsigned)__builtin_amdgcn_readlane((int)kl, 63);
            unsigned long long bk = (((unsigned long long)mh) << 32) | ml;
            if (localk == bk && bslot >= 0) chosen |= 1u << (bslot >> 6);
            if (lane == 0) nbr[s * K_ + k] = (int)(bk & 0xFFFFFFFFull);
        }
    }
    if (lane == 0) {
        for (int k = kcnt; k < K_; ++k) nbr[s * K_ + k] = -1;
        cntv[s] = (float)kcnt;
    }
}

// ---------------- message MLP v5: bf16 MFMA, pre-converted x ----------------
__global__ __launch_bounds__(256) void msg_kernel(
    const ushort_t* __restrict__ xb, const float* __restrict__ pos,
    const float* __restrict__ W1, const float* __restrict__ b1,
    const float* __restrict__ W2, const float* __restrict__ b2,
    const float* __restrict__ pos_s, const int* __restrict__ nbr,
    const float* __restrict__ cntv, float* __restrict__ aggr_x,
    float* __restrict__ out_pos)
{
    __shared__ __align__(16) char smem[4 * 5120];
    const int t = threadIdx.x;
    const int wv = t >> 6, lane = t & 63;
    const int quad = lane >> 4, cl = lane & 15;
    char* wb = smem + wv * 5120;

    short8 bfrag[8][2];
    float b1v[8], w1dv[8], w2v0[8], w2v1[8], w2v2[8];
#pragma unroll
    for (int Nt = 0; Nt < 8; ++Nt) {
        const int h = Nt * 16 + cl;
#pragma unroll
        for (int ks = 0; ks < 2; ++ks) {
            short8 f;
#pragma unroll
            for (int jj = 0; jj < 8; ++jj)
                f[jj] = f2bf(W1[(ks * 32 + quad * 8 + jj) * H_ + h]);
            bfrag[Nt][ks] = f;
        }
        b1v[Nt] = b1[h];
        w1dv[Nt] = W1[64 * H_ + h];
        w2v0[Nt] = W2[h * 3 + 0];
        w2v1[Nt] = W2[h * 3 + 1];
        w2v2[Nt] = W2[h * 3 + 2];
    }
    const float b20 = b2[0], b21 = b2[1], b22 = b2[2];

    const int kkg = lane >> 1, half = lane & 1;
    for (int i = 0; i < 4; ++i) {
        const int s = blockIdx.x * 16 + wv * 4 + i;
        const int b = s >> 10;
        const int n = nbr[s * K_ + kkg];
        {
            char* frow = wb + kkg * 144 + half * 64;
            if (n >= 0) {
                const short8* xr = (const short8*)(xb + ((size_t)b * N_ + n) * D_) + half * 4;
#pragma unroll
                for (int q = 0; q < 4; ++q) *(short8*)(frow + q * 16) = xr[q];
            } else {
                short8 z = {0, 0, 0, 0, 0, 0, 0, 0};
#pragma unroll
                for (int q = 0; q < 4; ++q) *(short8*)(frow + q * 16) = z;
            }
            if (half == 0) {
                float dxm = 0.f, dym = 0.f, dzm = 0.f, de = -1.f;
                if (n >= 0) {
                    const float* pj = pos + ((size_t)b * N_ + n) * 3;
                    float dx = pj[0] - pos_s[s * 3 + 0];
                    float dy = pj[1] - pos_s[s * 3 + 1];
                    float dz = pj[2] - pos_s[s * 3 + 2];
                    float d2 = dx * dx + dy * dy + dz * dz;
                    de = d2 > 0.f ? sqrtf(d2) : 0.f;
                    dxm = dx; dym = dy; dzm = dz;
                }
                f32x4 sv = {dxm, dym, dzm, de};
                *(f32x4*)(wb + 4608 + kkg * 16) = sv;
            }
        }
        float agp[8] = {0, 0, 0, 0, 0, 0, 0, 0};
        float gp0[8] = {0, 0, 0, 0, 0, 0, 0, 0};
        float gp1[8] = {0, 0, 0, 0, 0, 0, 0, 0};
        float gp2[8] = {0, 0, 0, 0, 0, 0, 0, 0};
#pragma unroll
        for (int Mt = 0; Mt < 2; ++Mt) {
            short8 a0 = *(short8*)(wb + (Mt * 16 + cl) * 144 + quad * 16);
            short8 a1 = *(short8*)(wb + (Mt * 16 + cl) * 144 + 64 + quad * 16);
            f32x4 acc[8];
#pragma unroll
            for (int Nt = 0; Nt < 8; ++Nt) {
                f32x4 z = {0.f, 0.f, 0.f, 0.f};
                z = __builtin_amdgcn_mfma_f32_16x16x32_bf16(a0, bfrag[Nt][0], z, 0, 0, 0);
                z = __builtin_amdgcn_mfma_f32_16x16x32_bf16(a1, bfrag[Nt][1], z, 0, 0, 0);
                acc[Nt] = z;
            }
            f32x4 sd[4];
#pragma unroll
            for (int r = 0; r < 4; ++r)
                sd[r] = *(f32x4*)(wb + 4608 + (Mt * 16 + quad * 4 + r) * 16);
#pragma unroll
            for (int Nt = 0; Nt < 8; ++Nt) {
#pragma unroll
                for (int r = 0; r < 4; ++r) {
                    float dr = sd[r][3];
                    float wgt = dr >= 0.f ? 1.f : 0.f;
                    float dd = dr >= 0.f ? dr : 0.f;
                    float e = fmaf(dd, w1dv[Nt], acc[Nt][r]) + b1v[Nt];
                    e = e > 0.f ? e : 0.f;
                    agp[Nt] = fmaf(wgt, e, agp[Nt]);
                    gp0[Nt] = fmaf(sd[r][0], e, gp0[Nt]);
                    gp1[Nt] = fmaf(sd[r][1], e, gp1[Nt]);
                    gp2[Nt] = fmaf(sd[r][2], e, gp2[Nt]);
                }
            }
        }
#pragma unroll
        for (int Nt = 0; Nt < 8; ++Nt) {
            float v = agp[Nt]; v += __shfl_xor(v, 16); v += __shfl_xor(v, 32);
            aggr_x[(size_t)s * H_ + Nt * 16 + cl] = v;
            float g0 = gp0[Nt]; g0 += __shfl_xor(g0, 16); g0 += __shfl_xor(g0, 32); gp0[Nt] = g0;
            float g1 = gp1[Nt]; g1 += __shfl_xor(g1, 16); g1 += __shfl_xor(g1, 32); gp1[Nt] = g1;
            float g2 = gp2[Nt]; g2 += __shfl_xor(g2, 16); g2 += __shfl_xor(g2, 32); gp2[Nt] = g2;
        }
        float pr0 = 0.f, pr1 = 0.f, pr2 = 0.f;
#pragma unroll
        for (int Nt = 0; Nt < 8; ++Nt) {
            pr0 = fmaf(w2v0[Nt], gp0[Nt], pr0);
            pr1 = fmaf(w2v1[Nt], gp1[Nt], pr1);
            pr2 = fmaf(w2v2[Nt], gp2[Nt], pr2);
        }
#pragma unroll
        for (int off = 1; off < 16; off <<= 1) {
            pr0 += __shfl_xor(pr0, off);
            pr1 += __shfl_xor(pr1, off);
            pr2 += __shfl_xor(pr2, off);
        }
        f32x4 dsv = *(f32x4*)(wb + 4608 + (lane & 31) * 16);
        float q0 = dsv[0], q1 = dsv[1], q2 = dsv[2];
#pragma unroll
        for (int off = 1; off < 32; off <<= 1) {
            q0 += __shfl_xor(q0, off);
            q1 += __shfl_xor(q1, off);
            q2 += __shfl_xor(q2, off);
        }
        float cnt = cntv[s]; if (cnt < 1.f) cnt = 1.f;
        if (lane < 3) {
            float pr = lane == 0 ? pr0 : (lane == 1 ? pr1 : pr2);
            float qq = lane == 0 ? q0 : (lane == 1 ? q1 : q2);
            float bb = lane == 0 ? b20 : (lane == 1 ? b21 : b22);
            out_pos[s * 3 + lane] = pos_s[s * 3 + lane] + (pr + bb * qq) / cnt;
        }
    }
}

// ---------------- update GEMM: relu([x_d, aggr_x] @ W3 + b3) ----------------
__global__ __launch_bounds__(128) void out_kernel(
    const float* __restrict__ x, const float* __restrict__ W3,
    const float* __restrict__ b3, const int* __restrict__ idx_i,
    const float* __restrict__ aggr_x, float* __restrict__ out_x)
{
    __shared__ float rows[32][208];
    const int t = threadIdx.x;
    const int s0 = blockIdx.x * 32;
    const int sl = t >> 2, part = t & 3;
    const int s = s0 + sl;
    const int b = s >> 10;
    const int id = idx_i[s];
    {
        const float4* xr = (const float4*)(x + ((size_t)b * N_ + id) * D_);
        float4* rr = (float4*)&rows[sl][0];
#pragma unroll
        for (int q = 0; q < 4; ++q) rr[part * 4 + q] = xr[part * 4 + q];
        const float4* ar = (const float4*)(aggr_x + (size_t)s * H_);
        float4* rr2 = (float4*)&rows[sl][64];
#pragma unroll
        for (int q = 0; q < 8; ++q) rr2[part * 8 + q] = ar[part * 8 + q];
    }
    __syncthreads();
    float acc[32];
#pragma unroll
    for (int i = 0; i < 32; ++i) acc[i] = 0.f;
    for (int j4 = 0; j4 < 48; ++j4) {
        float w0 = W3[(j4 * 4 + 0) * H_ + t];
        float w1 = W3[(j4 * 4 + 1) * H_ + t];
        float w2 = W3[(j4 * 4 + 2) * H_ + t];
        float w3 = W3[(j4 * 4 + 3) * H_ + t];
#pragma unroll
        for (int i = 0; i < 32; ++i) {
            const float4 f = *(const float4*)&rows[i][j4 * 4];
            float a = acc[i];
            a = fmaf(f.x, w0, a); a = fmaf(f.y, w1, a);
            a = fmaf(f.z, w2, a); a = fmaf(f.w, w3, a);
            acc[i] = a;
        }
    }
    const float bb = b3[t];
#pragma unroll
    for (int i = 0; i < 32; ++i) {
        float v = acc[i] + bb;
        v = v > 0.f ? v : 0.f;
        out_x[(size_t)(s0 + i) * H_ + t] = v;
    }
}

extern "C" void kernel_launch(void* const* d_in, const int* in_sizes, int n_in,
                              void* d_out, int out_size, void* d_ws, size_t ws_size,
                              hipStream_t stream) {
    const float* x   = (const float*)d_in[0];
    const float* pos = (const float*)d_in[1];
    const float* W1  = (const float*)d_in[2];
    const float* b1  = (const float*)d_in[3];
    const float* W2  = (const float*)d_in[4];
    const float* b2  = (const float*)d_in[5];
    const float* W3  = (const float*)d_in[6];
    const float* b3  = (const float*)d_in[7];

    float* out_x   = (float*)d_out;                       // [16,1024,128]
    float* out_pos = (float*)d_out + 2097152;             // [16,1024,3]
    float* idx_f   = (float*)d_out + 2146304;             // [16,1024] as float

    char* ws = (char*)d_ws;
    int*      idx_i  = (int*)ws;                   // 16384 ints
    float*    pos_s  = (float*)(ws + 65536);       // 49152 floats
    int*      nbr    = (int*)(ws + 262144);        // 524288 ints
    float*    cntv   = (float*)(ws + 2359296);     // 16384 floats
    float*    aggr_x = (float*)(ws + 2424832);     // 2097152 floats
    ushort_t* x_bf16 = (ushort_t*)(ws + 10813440); // 16777216 ushorts (ends ~19.2MB)

    cvt_kernel<<<(B_ * N_ * D_) / (256 * 8), 256, 0, stream>>>(x, x_bf16);
    fps_kernel<<<B_, 256, 0, stream>>>(pos, idx_i, idx_f, pos_s);
    nbr_kernel<<<(B_ * NS_) / 4, 256, 0, stream>>>(pos, pos_s, nbr, cntv);
    msg_kernel<<<(B_ * NS_) / 16, 256, 0, stream>>>(x_bf16, pos, W1, b1, W2, b2,
                                                    pos_s, nbr, cntv, aggr_x, out_pos);
    out_kernel<<<(B_ * NS_) / 32, 128, 0, stream>>>(x, W3, b3, idx_i, aggr_x, out_x);
}